// Round 1
// baseline (164979.077 us; speedup 1.0000x reference)
//
#include <hip/hip_runtime.h>

#define NBATCH 64
#define NT 2048
#define NI 128
#define NH 256
#define NGROUP 8
#define WPG 32
#define BPG 8

__device__ __forceinline__ float sigm(float v) {
  return 1.0f / (1.0f + __expf(-v));
}
__device__ __forceinline__ float tanh_fast(float v) {
  v = fminf(fmaxf(v, -15.0f), 15.0f);
  float e = __expf(-2.0f * v);
  return (1.0f - e) / (1.0f + e);
}

// 256 WGs x 512 threads. group g = bid&7 (8 batches each), WG j = bid>>3 owns
// units [8j,8j+8) of BOTH layers. Weights live in VGPRs (thread = (row, k-slice),
// reused across the group's 8 batches). h state exchanged via global d_ws with
// agent-scope acquire/release flags; 96KB LDS forces 1 WG/CU => all co-resident.
__global__ __launch_bounds__(512, 2) void lstm_persistent(
    const float* __restrict__ x,
    const float* __restrict__ wih0, const float* __restrict__ whh0,
    const float* __restrict__ bih0, const float* __restrict__ bhh0,
    const float* __restrict__ wih1, const float* __restrict__ whh1,
    const float* __restrict__ bih1, const float* __restrict__ bhh1,
    const float* __restrict__ fcw, const float* __restrict__ fcb,
    float* __restrict__ out,
    float* __restrict__ h0buf, float* __restrict__ h1buf,
    int* __restrict__ flags0, int* __restrict__ flags1)
{
  extern __shared__ float sm[];
  float* zz   = sm;                 // [8][384]  = [x_t(128) | h0(256)]
  float* zh1  = zz + 8 * 384;       // [8][256]  = h1(t-1)
  float* pL0  = zh1 + 8 * 256;      // [8][32][8] partials
  float* pL1  = pL0 + 8 * 32 * 8;   // [8][32][8]
  float* gbuf = pL1 + 8 * 32 * 8;   // [32][8]
  float* bias = gbuf + 32 * 8;      // [64]

  const int tid = threadIdx.x;
  const int bid = blockIdx.x;
  const int g = bid & 7;
  const int j = bid >> 3;
  const int b0 = g * BPG;
  int* f0 = flags0 + g * WPG;
  int* f1 = flags1 + g * WPG;

  const bool isL0 = (tid < 256);
  const int r = tid & 31;            // row-local 0..31 (gate*8 + ulocal)
  const int s = (tid & 255) >> 5;    // k-slice 0..7
  const int gate = r >> 3;
  const int ul = r & 7;
  const int R = gate * NH + j * 8 + ul;  // global gate row 0..1023

  // ---- load weights into registers (static indexing only!) ----
  float wreg[64];
  if (isL0) {
    const int kbase = s * 48;                 // dot = [x(128)|h0(256)] = 384
#pragma unroll
    for (int kk = 0; kk < 48; ++kk) {
      int k = kbase + kk;
      wreg[kk] = (k < NI) ? wih0[R * NI + k] : whh0[R * NH + (k - NI)];
    }
#pragma unroll
    for (int kk = 48; kk < 64; ++kk) wreg[kk] = 0.0f;
  } else {
    const int kbase = s * 64;                 // dot = [h0(256)|h1(256)] = 512
#pragma unroll
    for (int kk = 0; kk < 64; ++kk) {
      int k = kbase + kk;
      wreg[kk] = (k < NH) ? wih1[R * NH + k] : whh1[R * NH + (k - NH)];
    }
  }
  if (tid < 32) bias[tid] = bih0[R] + bhh0[R];
  else if (tid < 64) bias[tid] = bih1[R] + bhh1[R];

  // zero initial h0 part of zz (h0(-1) = 0)
  if (tid < 256) {
    int b = tid >> 5, k8 = (tid & 31) * 8;
#pragma unroll
    for (int q = 0; q < 8; ++q) zz[b * 384 + 128 + k8 + q] = 0.0f;
  }
  float c0 = 0.0f, c1 = 0.0f;  // cell state held by threads 0..63 as (u,b)
  __syncthreads();

  for (int t = 0; t < NT; ++t) {
    // ---- ph1: wait peers finished step t-1 (flags hold #completed steps) ----
    if (tid < WPG) {
      int guard = 0;
      while (__hip_atomic_load(&f0[tid], __ATOMIC_ACQUIRE, __HIP_MEMORY_SCOPE_AGENT) < t) {
        __builtin_amdgcn_s_sleep(1);
        if (++guard > 200000000) break;
      }
    } else if (tid < 2 * WPG) {
      const int p = tid - WPG;
      int guard = 0;
      while (__hip_atomic_load(&f1[p], __ATOMIC_ACQUIRE, __HIP_MEMORY_SCOPE_AGENT) < t) {
        __builtin_amdgcn_s_sleep(1);
        if (++guard > 200000000) break;
      }
    }
    __syncthreads();
    // ---- ph1b: stage x_t (tid<256) and h1(t-1) (tid>=256) ----
    if (tid < 256) {
      const int b = tid >> 5, i4 = (tid & 31) * 4;
      const float4 v = *reinterpret_cast<const float4*>(
          x + ((size_t)(b0 + b) * NT + (size_t)t) * NI + i4);
      *reinterpret_cast<float4*>(&zz[b * 384 + i4]) = v;
    } else {
      const int p = tid - 256;
      const int b = p >> 5, k8 = (p & 31) * 8;
      const float* src = h1buf + ((size_t)((t + 1) & 1) * NBATCH + (b0 + b)) * NH + k8;
      const float4 v0 = *reinterpret_cast<const float4*>(src);
      const float4 v1 = *reinterpret_cast<const float4*>(src + 4);
      *reinterpret_cast<float4*>(&zh1[b * 256 + k8]) = v0;
      *reinterpret_cast<float4*>(&zh1[b * 256 + k8 + 4]) = v1;
    }
    __syncthreads();
    // ---- ph2: L0 full dot; L1 h1-half (slices 4..7) ----
    if (isL0) {
      float acc[8];
#pragma unroll
      for (int b = 0; b < 8; ++b) acc[b] = 0.0f;
      const int kb = s * 48;
#pragma unroll
      for (int c = 0; c < 12; ++c) {
        float4 h4[8];
#pragma unroll
        for (int b = 0; b < 8; ++b)
          h4[b] = *reinterpret_cast<const float4*>(&zz[b * 384 + kb + c * 4]);
#pragma unroll
        for (int b = 0; b < 8; ++b) {
          acc[b] = fmaf(wreg[c * 4 + 0], h4[b].x, acc[b]);
          acc[b] = fmaf(wreg[c * 4 + 1], h4[b].y, acc[b]);
          acc[b] = fmaf(wreg[c * 4 + 2], h4[b].z, acc[b]);
          acc[b] = fmaf(wreg[c * 4 + 3], h4[b].w, acc[b]);
        }
      }
      float* pd = &pL0[(s * 32 + r) * 8];
      *reinterpret_cast<float4*>(pd) = make_float4(acc[0], acc[1], acc[2], acc[3]);
      *reinterpret_cast<float4*>(pd + 4) = make_float4(acc[4], acc[5], acc[6], acc[7]);
    } else if (s >= 4) {
      float acc[8];
#pragma unroll
      for (int b = 0; b < 8; ++b) acc[b] = 0.0f;
      const int kb = (s - 4) * 64;
#pragma unroll
      for (int c = 0; c < 16; ++c) {
        float4 h4[8];
#pragma unroll
        for (int b = 0; b < 8; ++b)
          h4[b] = *reinterpret_cast<const float4*>(&zh1[b * 256 + kb + c * 4]);
#pragma unroll
        for (int b = 0; b < 8; ++b) {
          acc[b] = fmaf(wreg[c * 4 + 0], h4[b].x, acc[b]);
          acc[b] = fmaf(wreg[c * 4 + 1], h4[b].y, acc[b]);
          acc[b] = fmaf(wreg[c * 4 + 2], h4[b].z, acc[b]);
          acc[b] = fmaf(wreg[c * 4 + 3], h4[b].w, acc[b]);
        }
      }
      float* pd = &pL1[(s * 32 + r) * 8];
      *reinterpret_cast<float4*>(pd) = make_float4(acc[0], acc[1], acc[2], acc[3]);
      *reinterpret_cast<float4*>(pd + 4) = make_float4(acc[4], acc[5], acc[6], acc[7]);
    }
    __syncthreads();
    // ---- ph3: L0 reduce + gates + publish h0(t) ----
    if (tid < 256) {
      const int rr = tid >> 3, b = tid & 7;
      float sum = bias[rr];
#pragma unroll
      for (int s2 = 0; s2 < 8; ++s2) sum += pL0[(s2 * 32 + rr) * 8 + b];
      gbuf[rr * 8 + b] = sum;
    }
    __syncthreads();
    if (tid < 64) {
      const int u = tid >> 3, b = tid & 7;
      const float gi = gbuf[(0 * 8 + u) * 8 + b];
      const float gf = gbuf[(1 * 8 + u) * 8 + b];
      const float gg = gbuf[(2 * 8 + u) * 8 + b];
      const float go = gbuf[(3 * 8 + u) * 8 + b];
      const float ii = sigm(gi), ff = sigm(gf), gt = tanh_fast(gg), oo = sigm(go);
      c0 = ff * c0 + ii * gt;
      const float h = oo * tanh_fast(c0);
      h0buf[((size_t)(t & 1) * NBATCH + (b0 + b)) * NH + j * 8 + u] = h;
    }
    __threadfence();
    __syncthreads();
    if (tid == 0)
      __hip_atomic_store(&f0[j], t + 1, __ATOMIC_RELEASE, __HIP_MEMORY_SCOPE_AGENT);
    // ---- ph4: wait all h0(t) slices, stage into zz (also feeds next step's L0) ----
    if (tid < WPG) {
      int guard = 0;
      while (__hip_atomic_load(&f0[tid], __ATOMIC_ACQUIRE, __HIP_MEMORY_SCOPE_AGENT) < t + 1) {
        __builtin_amdgcn_s_sleep(1);
        if (++guard > 200000000) break;
      }
    }
    __syncthreads();
    if (tid < 256) {
      const int b = tid >> 5, k8 = (tid & 31) * 8;
      const float* src = h0buf + ((size_t)(t & 1) * NBATCH + (b0 + b)) * NH + k8;
      const float4 v0 = *reinterpret_cast<const float4*>(src);
      const float4 v1 = *reinterpret_cast<const float4*>(src + 4);
      *reinterpret_cast<float4*>(&zz[b * 384 + 128 + k8]) = v0;
      *reinterpret_cast<float4*>(&zz[b * 384 + 128 + k8 + 4]) = v1;
    }
    __syncthreads();
    // ---- ph5: L1 h0(t)-half (slices 0..3) ----
    if (!isL0 && s < 4) {
      float acc[8];
#pragma unroll
      for (int b = 0; b < 8; ++b) acc[b] = 0.0f;
      const int kb = s * 64;
#pragma unroll
      for (int c = 0; c < 16; ++c) {
        float4 h4[8];
#pragma unroll
        for (int b = 0; b < 8; ++b)
          h4[b] = *reinterpret_cast<const float4*>(&zz[b * 384 + 128 + kb + c * 4]);
#pragma unroll
        for (int b = 0; b < 8; ++b) {
          acc[b] = fmaf(wreg[c * 4 + 0], h4[b].x, acc[b]);
          acc[b] = fmaf(wreg[c * 4 + 1], h4[b].y, acc[b]);
          acc[b] = fmaf(wreg[c * 4 + 2], h4[b].z, acc[b]);
          acc[b] = fmaf(wreg[c * 4 + 3], h4[b].w, acc[b]);
        }
      }
      float* pd = &pL1[(s * 32 + r) * 8];
      *reinterpret_cast<float4*>(pd) = make_float4(acc[0], acc[1], acc[2], acc[3]);
      *reinterpret_cast<float4*>(pd + 4) = make_float4(acc[4], acc[5], acc[6], acc[7]);
    }
    __syncthreads();
    // ---- ph6: L1 reduce + gates + publish h1(t) ----
    if (tid < 256) {
      const int rr = tid >> 3, b = tid & 7;
      float sum = bias[32 + rr];
#pragma unroll
      for (int s2 = 0; s2 < 8; ++s2) sum += pL1[(s2 * 32 + rr) * 8 + b];
      gbuf[rr * 8 + b] = sum;
    }
    __syncthreads();
    if (tid < 64) {
      const int u = tid >> 3, b = tid & 7;
      const float gi = gbuf[(0 * 8 + u) * 8 + b];
      const float gf = gbuf[(1 * 8 + u) * 8 + b];
      const float gg = gbuf[(2 * 8 + u) * 8 + b];
      const float go = gbuf[(3 * 8 + u) * 8 + b];
      const float ii = sigm(gi), ff = sigm(gf), gt = tanh_fast(gg), oo = sigm(go);
      c1 = ff * c1 + ii * gt;
      const float h = oo * tanh_fast(c1);
      h1buf[((size_t)(t & 1) * NBATCH + (b0 + b)) * NH + j * 8 + u] = h;
    }
    __threadfence();
    __syncthreads();
    if (tid == 0)
      __hip_atomic_store(&f1[j], t + 1, __ATOMIC_RELEASE, __HIP_MEMORY_SCOPE_AGENT);
  }

  // ---- epilogue: fc over relu(h1[T-1]) by WG j==0 of each group ----
  if (j == 0) {
    if (tid < WPG) {
      int guard = 0;
      while (__hip_atomic_load(&f1[tid], __ATOMIC_ACQUIRE, __HIP_MEMORY_SCOPE_AGENT) < NT) {
        __builtin_amdgcn_s_sleep(1);
        if (++guard > 200000000) break;
      }
    }
    __syncthreads();
    const int bb = tid >> 6, lane = tid & 63;  // 8 waves = 8 batches
    const float* hrow = h1buf + ((size_t)1 * NBATCH + (b0 + bb)) * NH; // (NT-1)&1 == 1
    const float4 h4 = *reinterpret_cast<const float4*>(hrow + lane * 4);
    const float4 w4 = *reinterpret_cast<const float4*>(fcw + lane * 4);
    float p = fmaxf(h4.x, 0.f) * w4.x + fmaxf(h4.y, 0.f) * w4.y +
              fmaxf(h4.z, 0.f) * w4.z + fmaxf(h4.w, 0.f) * w4.w;
#pragma unroll
    for (int off = 32; off >= 1; off >>= 1) p += __shfl_down(p, off, 64);
    if (lane == 0) out[b0 + bb] = p + fcb[0];
  }
}

extern "C" void kernel_launch(void* const* d_in, const int* in_sizes, int n_in,
                              void* d_out, int out_size, void* d_ws, size_t ws_size,
                              hipStream_t stream) {
  (void)in_sizes; (void)n_in; (void)out_size; (void)ws_size;
  const float* x    = (const float*)d_in[0];
  const float* wih0 = (const float*)d_in[1];
  const float* whh0 = (const float*)d_in[2];
  const float* bih0 = (const float*)d_in[3];
  const float* bhh0 = (const float*)d_in[4];
  const float* wih1 = (const float*)d_in[5];
  const float* whh1 = (const float*)d_in[6];
  const float* bih1 = (const float*)d_in[7];
  const float* bhh1 = (const float*)d_in[8];
  const float* fcw  = (const float*)d_in[9];
  const float* fcb  = (const float*)d_in[10];
  float* out = (float*)d_out;

  float* ws = (float*)d_ws;
  float* h0buf = ws;                        // [2][64][256] f32
  float* h1buf = ws + 2 * 64 * 256;         // [2][64][256] f32
  int* flags0 = (int*)(ws + 4 * 64 * 256);  // [8][32]
  int* flags1 = flags0 + 256;               // [8][32]

  const size_t zbytes = (size_t)(4 * 64 * 256) * sizeof(float) + 2 * 256 * sizeof(int);
  hipMemsetAsync(d_ws, 0, zbytes, stream);

  size_t shmem = 96 * 1024;  // pad to force 1 WG/CU (co-residency for flag sync)
  if (hipFuncSetAttribute(reinterpret_cast<const void*>(lstm_persistent),
                          hipFuncAttributeMaxDynamicSharedMemorySize,
                          (int)shmem) != hipSuccess) {
    shmem = 9536 * sizeof(float);  // real footprint, fits default 64KB limit
  }

  hipLaunchKernelGGL(lstm_persistent, dim3(256), dim3(512), shmem, stream,
                     x, wih0, whh0, bih0, bhh0, wih1, whh1, bih1, bhh1,
                     fcw, fcb, out, h0buf, h1buf, flags0, flags1);
}

// Round 2
// 13277.354 us; speedup vs baseline: 12.4256x; 12.4256x over previous
//
#include <hip/hip_runtime.h>

#define NT 2048
#define NI 128
#define NH 256
#define WPG 32
#define BPG 8

typedef unsigned long long u64;

__device__ __forceinline__ float sigm(float v) {
  return 1.0f / (1.0f + __expf(-v));
}
__device__ __forceinline__ float tanh_fast(float v) {
  v = fminf(fmaxf(v, -15.0f), 15.0f);
  float e = __expf(-2.0f * v);
  return (1.0f - e) / (1.0f + e);
}

// Cross-XCD-coherent, cache-maintenance-free accessors (relaxed agent => sc1
// route to coherent point; NO buffer_inv / buffer_wbl2, unlike acquire/release).
__device__ __forceinline__ int ld_flag(const int* p) {
  return __hip_atomic_load(p, __ATOMIC_RELAXED, __HIP_MEMORY_SCOPE_AGENT);
}
__device__ __forceinline__ void st_flag(int* p, int v) {
  __hip_atomic_store(p, v, __ATOMIC_RELAXED, __HIP_MEMORY_SCOPE_AGENT);
}
__device__ __forceinline__ void st_h(float* p, float v) {
  __hip_atomic_store(p, v, __ATOMIC_RELAXED, __HIP_MEMORY_SCOPE_AGENT);
}
__device__ __forceinline__ u64 ld_h64(const u64* p) {
  return __hip_atomic_load(p, __ATOMIC_RELAXED, __HIP_MEMORY_SCOPE_AGENT);
}

// 256 WGs x 512 threads, 1 WG/CU (forced by 96KB dyn LDS => all co-resident).
// group g = bid&7 owns batches [8g,8g+8); WG j = bid>>3 owns units [8j,8j+8)
// of BOTH layers. Weights in VGPRs. Layer-skewed schedule: iteration `it`
// computes L0(it) (tid<256) and L1(it-1) (tid>=256) in one phase — both only
// need h0(it-1), h1(it-2) => ONE flag wait per iteration.
__global__ __launch_bounds__(512, 2) void lstm_persistent(
    const float* __restrict__ x,
    const float* __restrict__ wih0, const float* __restrict__ whh0,
    const float* __restrict__ bih0, const float* __restrict__ bhh0,
    const float* __restrict__ wih1, const float* __restrict__ whh1,
    const float* __restrict__ bih1, const float* __restrict__ bhh1,
    const float* __restrict__ fcw, const float* __restrict__ fcb,
    float* __restrict__ out,
    float* __restrict__ h0buf, float* __restrict__ h1buf,
    int* __restrict__ flags)
{
  extern __shared__ float sm[];
  float* zz   = sm;                 // [8][640] = [x(128) | h0(t-1)(256) | h1(t-2)(256)]
  float* pL0  = zz + 8 * 640;       // [8][32][8]
  float* pL1  = pL0 + 2048;         // [8][32][8]
  float* gb   = pL1 + 2048;         // [64][8] (rows 0..31 = L0, 32..63 = L1)
  float* bias = gb + 512;           // [64]

  const int tid = threadIdx.x;
  const int bid = blockIdx.x;
  const int g = bid & 7;
  const int j = bid >> 3;
  const int b0 = g * BPG;
  int* fl = flags + g * WPG;

  const bool isL0 = (tid < 256);
  const int sub = tid & 255;
  const int r = sub & 31;            // local gate row = gate*8 + ulocal
  const int s = sub >> 5;            // k-slice 0..7
  const int gate = r >> 3;
  const int ul = r & 7;
  const int R = gate * NH + j * 8 + ul;

  // ---- weights into registers (static indexing) ----
  float wreg[64];
  if (isL0) {
    const int kbase = s * 48;                 // dot = [x(128)|h0(256)] = 384
#pragma unroll
    for (int kk = 0; kk < 48; ++kk) {
      int k = kbase + kk;
      wreg[kk] = (k < NI) ? wih0[R * NI + k] : whh0[R * NH + (k - NI)];
    }
#pragma unroll
    for (int kk = 48; kk < 64; ++kk) wreg[kk] = 0.0f;
  } else {
    const int kbase = s * 64;                 // dot = [h0(t)(256)|h1(t-1)(256)] = 512
#pragma unroll
    for (int kk = 0; kk < 64; ++kk) {
      int k = kbase + kk;
      wreg[kk] = (k < NH) ? wih1[R * NH + k] : whh1[R * NH + (k - NH)];
    }
  }
  if (tid < 32) bias[tid] = bih0[R] + bhh0[R];
  if (tid >= 256 && tid < 288) bias[32 + r] = bih1[R] + bhh1[R];

  // h0(-1) = 0 in LDS
  if (tid < 256) {
    const int b = tid >> 5, k8 = (tid & 31) * 8;
#pragma unroll
    for (int q = 0; q < 8; ++q) zz[b * 640 + 128 + k8 + q] = 0.0f;
  }
  float c0 = 0.0f, c1 = 0.0f;  // cells: tid<64 -> L0 (u,b); 64<=tid<128 -> L1
  __syncthreads();

  for (int it = 0; it <= NT; ++it) {
    // preload x (hides HBM/L2 latency under the flag wait)
    float4 xv = make_float4(0.f, 0.f, 0.f, 0.f);
    if (tid < 256 && it < NT) {
      const int b = tid >> 5, i4 = (tid & 31) * 4;
      xv = *reinterpret_cast<const float4*>(
          x + ((size_t)(b0 + b) * NT + (size_t)it) * NI + i4);
    }
    // ---- single wait point: peers published h0(it-1), h1(it-2) ----
    if (it > 0 && tid < WPG) {
      int guard = 0;
      while (ld_flag(&fl[tid]) < it) {
        __builtin_amdgcn_s_sleep(1);
        if (++guard > 100000000) break;
      }
    }
    __syncthreads();
    // ---- stage x, h0(it-1), h1(it-2) into LDS ----
    if (tid < 256) {
      const int b = tid >> 5, k8 = (tid & 31) * 8;
      if (it < NT)
        *reinterpret_cast<float4*>(&zz[b * 640 + (tid & 31) * 4]) = xv;
      // h1(it-2): parity (it-2)&1 == it&1 (memset zeros cover it<2)
      const u64* s1 = reinterpret_cast<const u64*>(
          h1buf + ((size_t)(it & 1) * 64 + (b0 + b)) * NH + k8);
      u64* d1 = reinterpret_cast<u64*>(&zz[b * 640 + 384 + k8]);
#pragma unroll
      for (int q = 0; q < 4; ++q) d1[q] = ld_h64(s1 + q);
    } else if (it >= 1) {
      const int p = tid - 256;
      const int b = p >> 5, k8 = (p & 31) * 8;
      const u64* s0 = reinterpret_cast<const u64*>(
          h0buf + ((size_t)((it - 1) & 1) * 64 + (b0 + b)) * NH + k8);
      u64* d0 = reinterpret_cast<u64*>(&zz[b * 640 + 128 + k8]);
#pragma unroll
      for (int q = 0; q < 4; ++q) d0[q] = ld_h64(s0 + q);
    }
    __syncthreads();
    // ---- compute: L0(it) on tid<256, L1(it-1) on tid>=256 ----
    if (isL0) {
      if (it < NT) {
        float acc[8];
#pragma unroll
        for (int b = 0; b < 8; ++b) acc[b] = 0.0f;
        const int kb = s * 48;
#pragma unroll
        for (int c = 0; c < 12; ++c) {
          float4 h4[8];
#pragma unroll
          for (int b = 0; b < 8; ++b)
            h4[b] = *reinterpret_cast<const float4*>(&zz[b * 640 + kb + c * 4]);
#pragma unroll
          for (int b = 0; b < 8; ++b) {
            acc[b] = fmaf(wreg[c * 4 + 0], h4[b].x, acc[b]);
            acc[b] = fmaf(wreg[c * 4 + 1], h4[b].y, acc[b]);
            acc[b] = fmaf(wreg[c * 4 + 2], h4[b].z, acc[b]);
            acc[b] = fmaf(wreg[c * 4 + 3], h4[b].w, acc[b]);
          }
        }
        float* pd = &pL0[(s * 32 + r) * 8];
        *reinterpret_cast<float4*>(pd) = make_float4(acc[0], acc[1], acc[2], acc[3]);
        *reinterpret_cast<float4*>(pd + 4) = make_float4(acc[4], acc[5], acc[6], acc[7]);
      }
    } else if (it >= 1) {
      float acc[8];
#pragma unroll
      for (int b = 0; b < 8; ++b) acc[b] = 0.0f;
      const int kb = s * 64;
#pragma unroll
      for (int c = 0; c < 16; ++c) {
        float4 h4[8];
#pragma unroll
        for (int b = 0; b < 8; ++b)
          h4[b] = *reinterpret_cast<const float4*>(&zz[b * 640 + 128 + kb + c * 4]);
#pragma unroll
        for (int b = 0; b < 8; ++b) {
          acc[b] = fmaf(wreg[c * 4 + 0], h4[b].x, acc[b]);
          acc[b] = fmaf(wreg[c * 4 + 1], h4[b].y, acc[b]);
          acc[b] = fmaf(wreg[c * 4 + 2], h4[b].z, acc[b]);
          acc[b] = fmaf(wreg[c * 4 + 3], h4[b].w, acc[b]);
        }
      }
      float* pd = &pL1[(s * 32 + r) * 8];
      *reinterpret_cast<float4*>(pd) = make_float4(acc[0], acc[1], acc[2], acc[3]);
      *reinterpret_cast<float4*>(pd + 4) = make_float4(acc[4], acc[5], acc[6], acc[7]);
    }
    __syncthreads();
    // ---- reduce partials -> gate pre-activations ----
    if (tid < 256) {
      if (it < NT) {
        const int rr = tid >> 3, b = tid & 7;
        float sum = bias[rr];
#pragma unroll
        for (int s2 = 0; s2 < 8; ++s2) sum += pL0[(s2 * 32 + rr) * 8 + b];
        gb[rr * 8 + b] = sum;
      }
    } else if (it >= 1) {
      const int p = tid - 256;
      const int rr = p >> 3, b = p & 7;
      float sum = bias[32 + rr];
#pragma unroll
      for (int s2 = 0; s2 < 8; ++s2) sum += pL1[(s2 * 32 + rr) * 8 + b];
      gb[(32 + rr) * 8 + b] = sum;
    }
    __syncthreads();
    // ---- gates + cell update + publish (sc1 stores) ----
    if (tid < 64) {
      if (it < NT) {
        const int u = tid >> 3, b = tid & 7;
        const float gi = gb[(0 * 8 + u) * 8 + b];
        const float gf = gb[(1 * 8 + u) * 8 + b];
        const float gg = gb[(2 * 8 + u) * 8 + b];
        const float go = gb[(3 * 8 + u) * 8 + b];
        const float ii = sigm(gi), ff = sigm(gf), gt = tanh_fast(gg), oo = sigm(go);
        c0 = ff * c0 + ii * gt;
        const float h = oo * tanh_fast(c0);
        st_h(&h0buf[((size_t)(it & 1) * 64 + (b0 + b)) * NH + j * 8 + u], h);
      }
    } else if (tid < 128 && it >= 1) {
      const int u = (tid & 63) >> 3, b = tid & 7;
      const float gi = gb[(32 + 0 * 8 + u) * 8 + b];
      const float gf = gb[(32 + 1 * 8 + u) * 8 + b];
      const float gg = gb[(32 + 2 * 8 + u) * 8 + b];
      const float go = gb[(32 + 3 * 8 + u) * 8 + b];
      const float ii = sigm(gi), ff = sigm(gf), gt = tanh_fast(gg), oo = sigm(go);
      c1 = ff * c1 + ii * gt;
      const float h = oo * tanh_fast(c1);
      st_h(&h1buf[((size_t)((it - 1) & 1) * 64 + (b0 + b)) * NH + j * 8 + u], h);
    }
    asm volatile("s_waitcnt vmcnt(0)" ::: "memory");  // h stores complete...
    __syncthreads();                                   // ...across all waves
    if (tid == 0) st_flag(&fl[j], it + 1);             // ...before flag
  }

  // ---- epilogue: FC over relu(h1[T-1]) by WG j==0 of each group ----
  if (j == 0) {
    if (tid < WPG) {
      int guard = 0;
      while (ld_flag(&fl[tid]) < NT + 1) {
        __builtin_amdgcn_s_sleep(1);
        if (++guard > 100000000) break;
      }
    }
    __syncthreads();
    const int bb = tid >> 6, lane = tid & 63;  // 8 waves = 8 batches
    const float* hrow = h1buf + ((size_t)(((NT - 1) & 1)) * 64 + (b0 + bb)) * NH;
    const u64 u0 = ld_h64(reinterpret_cast<const u64*>(hrow + lane * 4));
    const u64 u1 = ld_h64(reinterpret_cast<const u64*>(hrow + lane * 4 + 2));
    const float ha = __uint_as_float((unsigned)u0);
    const float hb = __uint_as_float((unsigned)(u0 >> 32));
    const float hc = __uint_as_float((unsigned)u1);
    const float hd = __uint_as_float((unsigned)(u1 >> 32));
    const float4 w4 = *reinterpret_cast<const float4*>(fcw + lane * 4);
    float p = fmaxf(ha, 0.f) * w4.x + fmaxf(hb, 0.f) * w4.y +
              fmaxf(hc, 0.f) * w4.z + fmaxf(hd, 0.f) * w4.w;
#pragma unroll
    for (int off = 32; off >= 1; off >>= 1) p += __shfl_down(p, off, 64);
    if (lane == 0) out[b0 + bb] = p + fcb[0];
  }
}

extern "C" void kernel_launch(void* const* d_in, const int* in_sizes, int n_in,
                              void* d_out, int out_size, void* d_ws, size_t ws_size,
                              hipStream_t stream) {
  (void)in_sizes; (void)n_in; (void)out_size; (void)ws_size;
  const float* x    = (const float*)d_in[0];
  const float* wih0 = (const float*)d_in[1];
  const float* whh0 = (const float*)d_in[2];
  const float* bih0 = (const float*)d_in[3];
  const float* bhh0 = (const float*)d_in[4];
  const float* wih1 = (const float*)d_in[5];
  const float* whh1 = (const float*)d_in[6];
  const float* bih1 = (const float*)d_in[7];
  const float* bhh1 = (const float*)d_in[8];
  const float* fcw  = (const float*)d_in[9];
  const float* fcb  = (const float*)d_in[10];
  float* out = (float*)d_out;

  float* ws = (float*)d_ws;
  float* h0buf = ws;                        // [2][64][256] f32
  float* h1buf = ws + 2 * 64 * 256;         // [2][64][256] f32
  int* flags = (int*)(ws + 4 * 64 * 256);   // [8][32]

  const size_t zbytes = (size_t)(4 * 64 * 256) * sizeof(float) + 256 * sizeof(int);
  hipMemsetAsync(d_ws, 0, zbytes, stream);

  size_t shmem = 96 * 1024;  // pad to force 1 WG/CU (co-residency + no CU sharing)
  if (hipFuncSetAttribute(reinterpret_cast<const void*>(lstm_persistent),
                          hipFuncAttributeMaxDynamicSharedMemorySize,
                          (int)shmem) != hipSuccess) {
    shmem = 9856 * sizeof(float);  // real footprint fallback
  }

  hipLaunchKernelGGL(lstm_persistent, dim3(256), dim3(512), shmem, stream,
                     x, wih0, whh0, bih0, bhh0, wih1, whh1, bih1, bhh1,
                     fcw, fcb, out, h0buf, h1buf, flags);
}

// Round 3
// 10148.943 us; speedup vs baseline: 16.2558x; 1.3082x over previous
//
#include <hip/hip_runtime.h>

#define NT 2048
#define NI 128
#define NH 256
#define WPG 32
#define BPG 8

typedef unsigned long long u64;

__device__ __forceinline__ float sigm(float v) {
  return 1.0f / (1.0f + __expf(-v));
}
__device__ __forceinline__ float tanh_fast(float v) {
  v = fminf(fmaxf(v, -15.0f), 15.0f);
  float e = __expf(-2.0f * v);
  return (1.0f - e) / (1.0f + e);
}

// relaxed agent-scope => coherent across XCDs, NO cache-maintenance ops.
__device__ __forceinline__ int ld_flag(const int* p) {
  return __hip_atomic_load(p, __ATOMIC_RELAXED, __HIP_MEMORY_SCOPE_AGENT);
}
__device__ __forceinline__ void st_flag(int* p, int v) {
  __hip_atomic_store(p, v, __ATOMIC_RELAXED, __HIP_MEMORY_SCOPE_AGENT);
}
__device__ __forceinline__ void st_h(float* p, float v) {
  __hip_atomic_store(p, v, __ATOMIC_RELAXED, __HIP_MEMORY_SCOPE_AGENT);
}
__device__ __forceinline__ u64 ld_h64(const u64* p) {
  return __hip_atomic_load(p, __ATOMIC_RELAXED, __HIP_MEMORY_SCOPE_AGENT);
}

// 256 WGs x 512 threads, 1 WG/CU. Group g=bid&7 owns batches [8g,8g+8);
// WG j=bid>>3 owns units [8j,8j+8) of both layers; weights in VGPRs.
// Batch half-sets A (b 0-3) / B (b 4-7) software-pipelined: the coherent-point
// round trip (publish -> flag -> poll -> load) for half X hides under the
// other half's dot/gates compute. Layer-skewed: block (X,it) computes
// L0_X(it) and L1_X(it-1).
__global__ __launch_bounds__(512, 2) void lstm_persistent(
    const float* __restrict__ x,
    const float* __restrict__ wih0, const float* __restrict__ whh0,
    const float* __restrict__ bih0, const float* __restrict__ bhh0,
    const float* __restrict__ wih1, const float* __restrict__ whh1,
    const float* __restrict__ bih1, const float* __restrict__ bhh1,
    const float* __restrict__ fcw, const float* __restrict__ fcb,
    float* __restrict__ out,
    float* __restrict__ h0buf, float* __restrict__ h1buf,
    int* __restrict__ flags)
{
  extern __shared__ float sm[];
  float* zz   = sm;                 // [4][640] = [x(128)|h0(256)|h1(256)] per batch
  float* pL0  = zz + 4 * 640;       // [8][4][32]  (s, b, r) -> bank = r
  float* pL1  = pL0 + 1024;         // [8][4][32]
  float* bias = pL1 + 1024;         // [64]

  const int tid = threadIdx.x;
  const int bid = blockIdx.x;
  const int g = bid & 7;
  const int j = bid >> 3;
  const int b0 = g * BPG;
  int* fA = flags + g * WPG;
  int* fB = flags + 256 + g * WPG;

  const bool isL0 = (tid < 256);
  const int lt = tid & 255;
  const int r = lt & 31;             // gate row local: gate*8 + u
  const int s = lt >> 5;             // k-slice 0..7
  const int gate = r >> 3;
  const int R = gate * NH + j * 8 + (r & 7);

  // ---- weights into registers ----
  float wreg[64];
  if (isL0) {
    const int kbase = s * 48;                 // [x(128)|h0(256)] = 384
#pragma unroll
    for (int kk = 0; kk < 48; ++kk) {
      int k = kbase + kk;
      wreg[kk] = (k < NI) ? wih0[R * NI + k] : whh0[R * NH + (k - NI)];
    }
#pragma unroll
    for (int kk = 48; kk < 64; ++kk) wreg[kk] = 0.0f;
  } else {
    const int kbase = s * 64;                 // [h0(256)|h1(256)] = 512
#pragma unroll
    for (int kk = 0; kk < 64; ++kk) {
      int k = kbase + kk;
      wreg[kk] = (k < NH) ? wih1[R * NH + k] : whh1[R * NH + (k - NH)];
    }
  }
  if (tid < 32) bias[tid] = bih0[R] + bhh0[R];
  if (tid >= 256 && tid < 288) bias[32 + r] = bih1[R] + bhh1[R];

  float cellA = 0.0f, cellB = 0.0f;  // cells: tid<128 -> L0(r,b); tid 256..383 -> L1
  // staged regs for the UPCOMING block (prologue = A(0): h's are zero)
  u64 rh0 = 0, rh1 = 0;
  float4 xv = make_float4(0.f, 0.f, 0.f, 0.f);
  if (tid < 128) {
    const int b = tid >> 5, i4 = (tid & 31) * 4;
    xv = *reinterpret_cast<const float4*>(
        x + ((size_t)(b0 + b) * NT + 0) * NI + i4);
  }
  __syncthreads();

  for (int it = 0; it <= NT; ++it) {
#pragma unroll 1
    for (int half = 0; half < 2; ++half) {
      const int xb = half ? 4 : 0;           // this block's batch sub-base
      int* fSelf  = half ? fB : fA;
      int* fOther = half ? fA : fB;
      const int nit = half ? (it + 1) : it;  // prefetch-target iteration
      const int oxb = half ? 0 : 4;          // prefetch-target batch sub-base

      // ---- 1. staged regs -> LDS ----
      if (tid < 256) {
        if (tid < 128 && it < NT) {
          const int b = tid >> 5, i4 = (tid & 31) * 4;
          *reinterpret_cast<float4*>(&zz[b * 640 + i4]) = xv;
        }
        // h0 piece: m = q*256 + tid, b = m>>7, off = m&127 (lane-contiguous)
        {
          const int m0 = tid, m1 = 256 + tid;
          *reinterpret_cast<u64*>(&zz[(m0 >> 7) * 640 + 128 + (m0 & 127) * 2]) = rh0;
          *reinterpret_cast<u64*>(&zz[(m1 >> 7) * 640 + 128 + (m1 & 127) * 2]) = rh1;
        }
      } else {
        const int p = tid - 256;
        const int m0 = p, m1 = 256 + p;
        *reinterpret_cast<u64*>(&zz[(m0 >> 7) * 640 + 384 + (m0 & 127) * 2]) = rh0;
        *reinterpret_cast<u64*>(&zz[(m1 >> 7) * 640 + 384 + (m1 & 127) * 2]) = rh1;
      }
      __syncthreads();

      // ---- 2. dots: L0_X(it) on tid<256 ; L1_X(it-1) on tid>=256 ----
      if (isL0) {
        if (it < NT) {
          float acc0 = 0.f, acc1 = 0.f, acc2 = 0.f, acc3 = 0.f;
          const int kb = s * 48;
#pragma unroll
          for (int c = 0; c < 12; ++c) {
            const float4 h0v = *reinterpret_cast<const float4*>(&zz[0 * 640 + kb + c * 4]);
            const float4 h1v = *reinterpret_cast<const float4*>(&zz[1 * 640 + kb + c * 4]);
            const float4 h2v = *reinterpret_cast<const float4*>(&zz[2 * 640 + kb + c * 4]);
            const float4 h3v = *reinterpret_cast<const float4*>(&zz[3 * 640 + kb + c * 4]);
            const float w0 = wreg[c * 4 + 0], w1 = wreg[c * 4 + 1];
            const float w2 = wreg[c * 4 + 2], w3 = wreg[c * 4 + 3];
            acc0 = fmaf(w0, h0v.x, fmaf(w1, h0v.y, fmaf(w2, h0v.z, fmaf(w3, h0v.w, acc0))));
            acc1 = fmaf(w0, h1v.x, fmaf(w1, h1v.y, fmaf(w2, h1v.z, fmaf(w3, h1v.w, acc1))));
            acc2 = fmaf(w0, h2v.x, fmaf(w1, h2v.y, fmaf(w2, h2v.z, fmaf(w3, h2v.w, acc2))));
            acc3 = fmaf(w0, h3v.x, fmaf(w1, h3v.y, fmaf(w2, h3v.z, fmaf(w3, h3v.w, acc3))));
          }
          pL0[s * 128 + 0 * 32 + r] = acc0;
          pL0[s * 128 + 1 * 32 + r] = acc1;
          pL0[s * 128 + 2 * 32 + r] = acc2;
          pL0[s * 128 + 3 * 32 + r] = acc3;
        }
      } else if (it >= 1) {
        float acc0 = 0.f, acc1 = 0.f, acc2 = 0.f, acc3 = 0.f;
        const int kb = s * 64;
#pragma unroll
        for (int c = 0; c < 16; ++c) {
          const float4 h0v = *reinterpret_cast<const float4*>(&zz[0 * 640 + 128 + kb + c * 4]);
          const float4 h1v = *reinterpret_cast<const float4*>(&zz[1 * 640 + 128 + kb + c * 4]);
          const float4 h2v = *reinterpret_cast<const float4*>(&zz[2 * 640 + 128 + kb + c * 4]);
          const float4 h3v = *reinterpret_cast<const float4*>(&zz[3 * 640 + 128 + kb + c * 4]);
          const float w0 = wreg[c * 4 + 0], w1 = wreg[c * 4 + 1];
          const float w2 = wreg[c * 4 + 2], w3 = wreg[c * 4 + 3];
          acc0 = fmaf(w0, h0v.x, fmaf(w1, h0v.y, fmaf(w2, h0v.z, fmaf(w3, h0v.w, acc0))));
          acc1 = fmaf(w0, h1v.x, fmaf(w1, h1v.y, fmaf(w2, h1v.z, fmaf(w3, h1v.w, acc1))));
          acc2 = fmaf(w0, h2v.x, fmaf(w1, h2v.y, fmaf(w2, h2v.z, fmaf(w3, h2v.w, acc2))));
          acc3 = fmaf(w0, h3v.x, fmaf(w1, h3v.y, fmaf(w2, h3v.z, fmaf(w3, h3v.w, acc3))));
        }
        pL1[s * 128 + 0 * 32 + r] = acc0;
        pL1[s * 128 + 1 * 32 + r] = acc1;
        pL1[s * 128 + 2 * 32 + r] = acc2;
        pL1[s * 128 + 3 * 32 + r] = acc3;
      }

      // ---- 3. wait other-half flags (overlapped with peers' compute) ----
      if (tid < WPG) {
        int guard = 0;
        while (ld_flag(&fOther[tid]) < nit) {
          __builtin_amdgcn_s_sleep(1);
          if (++guard > 100000000) break;
        }
      }
      __syncthreads();

      // ---- 4. prefetch next block's data into regs (latency hides under 5) ----
      if (nit <= NT) {
        const int p0 = (nit - 1) & 1;   // h0(nit-1) parity (nit=0 -> 1, zeros)
        const int p1 = nit & 1;         // h1(nit-2) parity
        if (tid < 256) {
          const int m0 = tid, m1 = 256 + tid;
          rh0 = ld_h64(reinterpret_cast<const u64*>(
              h0buf + ((size_t)p0 * 64 + (b0 + oxb + (m0 >> 7))) * NH + (m0 & 127) * 2));
          rh1 = ld_h64(reinterpret_cast<const u64*>(
              h0buf + ((size_t)p0 * 64 + (b0 + oxb + (m1 >> 7))) * NH + (m1 & 127) * 2));
          if (tid < 128 && nit < NT) {
            const int b = tid >> 5, i4 = (tid & 31) * 4;
            xv = *reinterpret_cast<const float4*>(
                x + ((size_t)(b0 + oxb + b) * NT + (size_t)nit) * NI + i4);
          }
        } else {
          const int p = tid - 256;
          const int m0 = p, m1 = 256 + p;
          rh0 = ld_h64(reinterpret_cast<const u64*>(
              h1buf + ((size_t)p1 * 64 + (b0 + oxb + (m0 >> 7))) * NH + (m0 & 127) * 2));
          rh1 = ld_h64(reinterpret_cast<const u64*>(
              h1buf + ((size_t)p1 * 64 + (b0 + oxb + (m1 >> 7))) * NH + (m1 & 127) * 2));
        }
      }

      // ---- 5. fused reduce + gates + publish ----
      if (tid < 128) {
        if (it < NT) {
          const int b = tid >> 5;       // 0..3
          float sum = bias[r];
#pragma unroll
          for (int s2 = 0; s2 < 8; ++s2) sum += pL0[s2 * 128 + b * 32 + r];
          // gate-quad exchange within wave (rows r, r^8, r^16, r^24 same u,b)
          const float v8  = __shfl_xor(sum, 8);
          const float v16 = __shfl_xor(sum, 16);
          const float v24 = __shfl_xor(v8, 16);
          float q0 = sum, q1 = v8, q2 = v16, q3 = v24, tq;
          if (gate & 1) { tq = q0; q0 = q1; q1 = tq; tq = q2; q2 = q3; q3 = tq; }
          if (gate & 2) { tq = q0; q0 = q2; q2 = tq; tq = q1; q1 = q3; q3 = tq; }
          const float ii = sigm(q0), ff = sigm(q1), gt = tanh_fast(q2), oo = sigm(q3);
          float c = (half ? cellB : cellA);
          c = ff * c + ii * gt;
          if (half) cellB = c; else cellA = c;
          const float h = oo * tanh_fast(c);
          if (r < 8)
            st_h(&h0buf[((size_t)(it & 1) * 64 + (b0 + xb + b)) * NH + j * 8 + r], h);
        }
      } else if (tid >= 256 && tid < 384 && it >= 1) {
        const int b = (tid - 256) >> 5;
        float sum = bias[32 + r];
#pragma unroll
        for (int s2 = 0; s2 < 8; ++s2) sum += pL1[s2 * 128 + b * 32 + r];
        const float v8  = __shfl_xor(sum, 8);
        const float v16 = __shfl_xor(sum, 16);
        const float v24 = __shfl_xor(v8, 16);
        float q0 = sum, q1 = v8, q2 = v16, q3 = v24, tq;
        if (gate & 1) { tq = q0; q0 = q1; q1 = tq; tq = q2; q2 = q3; q3 = tq; }
        if (gate & 2) { tq = q0; q0 = q2; q2 = tq; tq = q1; q1 = q3; q3 = tq; }
        const float ii = sigm(q0), ff = sigm(q1), gt = tanh_fast(q2), oo = sigm(q3);
        float c = (half ? cellB : cellA);
        c = ff * c + ii * gt;
        if (half) cellB = c; else cellA = c;
        const float h = oo * tanh_fast(c);
        if (r < 8)
          st_h(&h1buf[((size_t)((it - 1) & 1) * 64 + (b0 + xb + b)) * NH + j * 8 + r], h);
      }
      asm volatile("s_waitcnt vmcnt(0)" ::: "memory");  // publishes (+prefetch) done
      __syncthreads();
      if (tid == 0) st_flag(&fSelf[j], it + 1);
    }
  }

  // ---- epilogue: FC over relu(h1[T-1]) by WG j==0 of each group ----
  if (j == 0) {
    if (tid < WPG) {
      int guard = 0;
      while (ld_flag(&fA[tid]) < NT + 1 || ld_flag(&fB[tid]) < NT + 1) {
        __builtin_amdgcn_s_sleep(1);
        if (++guard > 100000000) break;
      }
    }
    __syncthreads();
    const int bb = tid >> 6, lane = tid & 63;  // 8 waves = 8 batches
    const float* hrow = h1buf + ((size_t)(((NT - 1) & 1)) * 64 + (b0 + bb)) * NH;
    const u64 u0 = ld_h64(reinterpret_cast<const u64*>(hrow + lane * 4));
    const u64 u1 = ld_h64(reinterpret_cast<const u64*>(hrow + lane * 4 + 2));
    const float ha = __uint_as_float((unsigned)u0);
    const float hb = __uint_as_float((unsigned)(u0 >> 32));
    const float hc = __uint_as_float((unsigned)u1);
    const float hd = __uint_as_float((unsigned)(u1 >> 32));
    const float4 w4 = *reinterpret_cast<const float4*>(fcw + lane * 4);
    float p = fmaxf(ha, 0.f) * w4.x + fmaxf(hb, 0.f) * w4.y +
              fmaxf(hc, 0.f) * w4.z + fmaxf(hd, 0.f) * w4.w;
#pragma unroll
    for (int off = 32; off >= 1; off >>= 1) p += __shfl_down(p, off, 64);
    if (lane == 0) out[b0 + bb] = p + fcb[0];
  }
}

extern "C" void kernel_launch(void* const* d_in, const int* in_sizes, int n_in,
                              void* d_out, int out_size, void* d_ws, size_t ws_size,
                              hipStream_t stream) {
  (void)in_sizes; (void)n_in; (void)out_size; (void)ws_size;
  const float* x    = (const float*)d_in[0];
  const float* wih0 = (const float*)d_in[1];
  const float* whh0 = (const float*)d_in[2];
  const float* bih0 = (const float*)d_in[3];
  const float* bhh0 = (const float*)d_in[4];
  const float* wih1 = (const float*)d_in[5];
  const float* whh1 = (const float*)d_in[6];
  const float* bih1 = (const float*)d_in[7];
  const float* bhh1 = (const float*)d_in[8];
  const float* fcw  = (const float*)d_in[9];
  const float* fcb  = (const float*)d_in[10];
  float* out = (float*)d_out;

  float* ws = (float*)d_ws;
  float* h0buf = ws;                        // [2][64][256] f32
  float* h1buf = ws + 2 * 64 * 256;         // [2][64][256] f32
  int* flags = (int*)(ws + 4 * 64 * 256);   // [2][8][32]

  const size_t zbytes = (size_t)(4 * 64 * 256) * sizeof(float) + 512 * sizeof(int);
  hipMemsetAsync(d_ws, 0, zbytes, stream);

  size_t shmem = 96 * 1024;  // force 1 WG/CU (co-residency, CU exclusivity)
  if (hipFuncSetAttribute(reinterpret_cast<const void*>(lstm_persistent),
                          hipFuncAttributeMaxDynamicSharedMemorySize,
                          (int)shmem) != hipSuccess) {
    shmem = 4672 * sizeof(float);  // real footprint fallback
  }

  hipLaunchKernelGGL(lstm_persistent, dim3(256), dim3(512), shmem, stream,
                     x, wih0, whh0, bih0, bhh0, wih1, whh1, bih1, bhh1,
                     fcw, fcb, out, h0buf, h1buf, flags);
}